// Round 6
// baseline (675.996 us; speedup 1.0000x reference)
//
#include <hip/hip_runtime.h>
#include <math.h>

#define NN 50000
#define DD 128
#define KK 16
#define CC 8
#define NCH 8                 // h stored chunk-major [NCH][NN][16]; 3.2MB/chunk < 4MiB L2
#define NB64 782              // ceil(NN/64)

typedef float v4f __attribute__((ext_vector_type(4)));
typedef int   v4i __attribute__((ext_vector_type(4)));

// ---- ws layout (bytes) ----
#define A_OFF    0u
#define B_OFF    (NN*DD*4u)               // 25,600,000
#define CENT_OFF (2u*NN*DD*4u)            // 51,200,000
#define Z0_OFF   (CENT_OFF + NN*4u)
#define Z1_OFF   (Z0_OFF + NN*4u)
#define F1_OFF   (Z1_OFF + NN*4u)
#define F2_OFF   (F1_OFF + NN*4u)
#define SU_OFF   (F2_OFF + NN*4u)         // 6 x u32 (f1 sums, slot per iter)
#define SD_OFF   (SU_OFF + 32u)           // 6 x double (f2 sums, slot per iter)
#define OACC_OFF (SD_OFF + 48u)           // 8 x double

// ---------------- feat @ W_gcn -> A (chunk-major [c][node][16]) ----------------
__global__ __launch_bounds__(256) void k_gemm(const float* __restrict__ feat,
    const float* __restrict__ W, float* __restrict__ A, double* __restrict__ oacc,
    unsigned* __restrict__ su, double* __restrict__ sd)
{
    __shared__ __align__(16) float sW[DD*DD];
    __shared__ float sF[64][DD+1];
    const int t = threadIdx.x;
    const int base = blockIdx.x * 64;
    if (blockIdx.x == 0) {
        if (t < 8) oacc[t] = 0.0;
        if (t < 6) { su[t] = 0u; sd[t] = 0.0; }
    }

    const float4* W4 = (const float4*)W;
    float4* sW4 = (float4*)sW;
    #pragma unroll
    for (int i = 0; i < 16; ++i) sW4[t + i*256] = W4[t + i*256];

    const v4f* F4 = (const v4f*)feat;
    #pragma unroll
    for (int e = t; e < 64*32; e += 256) {
        int row = e >> 5, q = e & 31;
        v4f v = (v4f)(0.f);
        if (base + row < NN) v = __builtin_nontemporal_load(&F4[(size_t)(base + row)*32 + q]);
        sF[row][q*4+0] = v.x; sF[row][q*4+1] = v.y;
        sF[row][q*4+2] = v.z; sF[row][q*4+3] = v.w;
    }
    __syncthreads();

    const int cg = t & 15;
    const int ng = t >> 4;
    const int cb = cg * 8;
    float acc[4][8];
    #pragma unroll
    for (int j=0;j<4;++j)
        #pragma unroll
        for (int c=0;c<8;++c) acc[j][c]=0.f;

    #pragma unroll 4
    for (int d = 0; d < DD; ++d) {
        float4 wa = *(const float4*)&sW[d*DD + cb];
        float4 wb = *(const float4*)&sW[d*DD + cb + 4];
        #pragma unroll
        for (int j=0;j<4;++j) {
            float f = sF[ng*4+j][d];
            acc[j][0] += f*wa.x; acc[j][1] += f*wa.y;
            acc[j][2] += f*wa.z; acc[j][3] += f*wa.w;
            acc[j][4] += f*wb.x; acc[j][5] += f*wb.y;
            acc[j][6] += f*wb.z; acc[j][7] += f*wb.w;
        }
    }
    const int ch = cb >> 4;
    const int co = cb & 15;
    #pragma unroll
    for (int j=0;j<4;++j) {
        int node = base + ng*4 + j;
        if (node < NN) {
            float4* dst = (float4*)&A[((size_t)ch*NN + node)*16 + co];
            dst[0] = make_float4(acc[j][0],acc[j][1],acc[j][2],acc[j][3]);
            dst[1] = make_float4(acc[j][4],acc[j][5],acc[j][6],acc[j][7]);
        }
    }
}

// ---------------- h0 = gather(A)+bg, fused center0 ----------------
// 782 co-resident blocks sweep 3.2MB chunks in phase; NT stores/loads keep the
// gather chunk as the only L2-retained working set.
__global__ __launch_bounds__(256) void k_agg0(const float* __restrict__ A,
    const int* __restrict__ nb, const float* __restrict__ bg,
    const float4* __restrict__ Wy4, const float* __restrict__ by,
    float* __restrict__ H, float* __restrict__ zold, int* __restrict__ center)
{
    __shared__ __align__(16) float sWy[DD*CC];
    __shared__ float sby[CC];
    const int t = threadIdx.x;
    ((float4*)sWy)[t] = Wy4[t];
    if (t < CC) sby[t] = by[t];
    __syncthreads();
    const int nl = t >> 2, q = t & 3;
    const int node = blockIdx.x*64 + nl;
    if (node >= NN) return;

    const v4f* A4 = (const v4f*)A;
    v4f* H4 = (v4f*)H;

    int idx[KK];
    const v4i* nbv = (const v4i*)(nb + (size_t)node*KK);
    #pragma unroll
    for (int k4 = 0; k4 < 4; ++k4) {
        v4i v = __builtin_nontemporal_load(&nbv[k4]);
        idx[k4*4+0]=v.x; idx[k4*4+1]=v.y; idx[k4*4+2]=v.z; idx[k4*4+3]=v.w;
    }
    float lg[CC];
    #pragma unroll
    for (int c=0;c<CC;++c) lg[c]=0.f;

    for (int c = 0; c < NCH; ++c) {
        v4f acc = ((const v4f*)bg)[c*4 + q];
        #pragma unroll
        for (int k=0;k<KK;++k)
            acc += A4[((size_t)c*NN + idx[k])*4 + q];     // cached: the chunk
        __builtin_nontemporal_store(acc, &H4[((size_t)c*NN + node)*4 + q]);
        const int d0 = c*16 + q*4;
        #pragma unroll
        for (int cls=0; cls<CC; ++cls)
            lg[cls] += acc.x*sWy[(d0+0)*CC+cls] + acc.y*sWy[(d0+1)*CC+cls]
                     + acc.z*sWy[(d0+2)*CC+cls] + acc.w*sWy[(d0+3)*CC+cls];
    }
    #pragma unroll
    for (int off=1; off<4; off<<=1)
        #pragma unroll
        for (int cls=0; cls<CC; ++cls) lg[cls] += __shfl_xor(lg[cls], off, 64);
    if (q == 0) {
        float bv = lg[0] + sby[0]; int bi = 0;
        #pragma unroll
        for (int cls=1; cls<CC; ++cls) {
            float v = lg[cls] + sby[cls];
            if (v > bv) { bv = v; bi = cls; }
        }
        center[node] = bi;
        zold[node] = 1.0f;
    }
}

// ---------------- f1, f2 per node + slot sums (u32 exact / f64) ----------------
__global__ __launch_bounds__(256) void k_stats(const int* __restrict__ center,
    const int* __restrict__ nb, float* __restrict__ f1o, float* __restrict__ f2o,
    unsigned* __restrict__ su2, double* __restrict__ sd2)
{
    const int t = threadIdx.x;
    const int i = blockIdx.x*256 + t;
    unsigned uf1 = 0, uf1sq = 0;
    double df2 = 0.0, df2sq = 0.0;
    if (i < NN) {
        const int ci = center[i];
        const int* nbi = nb + i*KK;
        unsigned long long cnt = 0ull;
        #pragma unroll
        for (int k=0;k<KK;++k) {
            int p = center[nbi[k]];
            cnt += 1ull << (p*8);
        }
        unsigned c1 = (unsigned)((cnt >> (ci*8)) & 0xFFull);
        float f2 = 0.f;
        #pragma unroll
        for (int c=0;c<CC;++c) {
            float fc = (float)((cnt >> (c*8)) & 0xFFull);
            fc = fmaxf(fc, 1e-5f);
            f2 -= fc * logf(fc);
        }
        f1o[i] = (float)c1;
        f2o[i] = f2;
        uf1 = c1; uf1sq = c1*c1;
        df2 = (double)f2; df2sq = df2*df2;
    }
    #pragma unroll
    for (int off = 32; off > 0; off >>= 1) {
        uf1   += __shfl_down(uf1,   off, 64);
        uf1sq += __shfl_down(uf1sq, off, 64);
        df2   += __shfl_down(df2,   off, 64);
        df2sq += __shfl_down(df2sq, off, 64);
    }
    __shared__ unsigned r1[4], r1s[4];
    __shared__ double   r2[4], r2s[4];
    const int wid = t >> 6, lane = t & 63;
    if (lane == 0) { r1[wid]=uf1; r1s[wid]=uf1sq; r2[wid]=df2; r2s[wid]=df2sq; }
    __syncthreads();
    if (t == 0) {
        atomicAdd(&su2[0], r1[0]+r1[1]+r1[2]+r1[3]);
        atomicAdd(&su2[1], r1s[0]+r1s[1]+r1s[2]+r1s[3]);
        atomicAdd(&sd2[0], r2[0]+r2[1]+r2[2]+r2[3]);
        atomicAdd(&sd2[1], r2s[0]+r2s[1]+r2s[2]+r2s[3]);
    }
}

// ---------------- h' = h + min(zold,z)*gather(h), fused next-center ----------------
__global__ __launch_bounds__(256) void k_update(const float* __restrict__ Hin,
    float* __restrict__ Hout, const int* __restrict__ nb,
    const float* __restrict__ f1, const float* __restrict__ f2,
    const float* __restrict__ zr, float* __restrict__ zw,
    const unsigned* __restrict__ su2, const double* __restrict__ sd2,
    const float* __restrict__ tau1, const float* __restrict__ tau2,
    const float4* __restrict__ Wy4, const float* __restrict__ by,
    int* __restrict__ center)
{
    __shared__ __align__(16) float sWy[DD*CC];
    __shared__ float sby[CC];
    const int t = threadIdx.x;
    ((float4*)sWy)[t] = Wy4[t];
    if (t < CC) sby[t] = by[t];
    __syncthreads();
    const int nl = t >> 2, q = t & 3;
    const int node = blockIdx.x*64 + nl;
    if (node >= NN) return;

    const v4f* Hin4 = (const v4f*)Hin;
    v4f* Hout4 = (v4f*)Hout;

    const double invN = 1.0 / (double)NN;
    double mu1  = (double)su2[0] * invN;
    double var1 = (double)su2[1] * invN - mu1*mu1;
    double is1  = 1.0 / sqrt(var1 + 1e-5);
    double mu2  = sd2[0] * invN;
    double var2 = sd2[1] * invN - mu2*mu2;
    double is2  = 1.0 / sqrt(var2 + 1e-5);
    float nf1 = (float)(((double)f1[node] - mu1) * is1);
    float nf2 = (float)(((double)f2[node] - mu2) * is2);
    float z = (1.0f/(1.0f + expf(nf1 - tau1[0]))) * (1.0f/(1.0f + expf(nf2 - tau2[0])));
    float gate = fminf(zr[node], z);
    if (q == 0) zw[node] = z;

    int idx[KK];
    const v4i* nbv = (const v4i*)(nb + (size_t)node*KK);
    #pragma unroll
    for (int k4 = 0; k4 < 4; ++k4) {
        v4i v = __builtin_nontemporal_load(&nbv[k4]);
        idx[k4*4+0]=v.x; idx[k4*4+1]=v.y; idx[k4*4+2]=v.z; idx[k4*4+3]=v.w;
    }
    float lg[CC];
    #pragma unroll
    for (int c=0;c<CC;++c) lg[c]=0.f;

    for (int c = 0; c < NCH; ++c) {
        v4f acc = (v4f)(0.f);
        #pragma unroll
        for (int k=0;k<KK;++k)
            acc += Hin4[((size_t)c*NN + idx[k])*4 + q];   // cached: the chunk
        v4f h = Hin4[((size_t)c*NN + node)*4 + q];        // cached: same chunk
        h += gate*acc;
        __builtin_nontemporal_store(h, &Hout4[((size_t)c*NN + node)*4 + q]);
        const int d0 = c*16 + q*4;
        #pragma unroll
        for (int cls=0; cls<CC; ++cls)
            lg[cls] += h.x*sWy[(d0+0)*CC+cls] + h.y*sWy[(d0+1)*CC+cls]
                     + h.z*sWy[(d0+2)*CC+cls] + h.w*sWy[(d0+3)*CC+cls];
    }
    #pragma unroll
    for (int off=1; off<4; off<<=1)
        #pragma unroll
        for (int cls=0; cls<CC; ++cls) lg[cls] += __shfl_xor(lg[cls], off, 64);
    if (q == 0) {
        float bv = lg[0] + sby[0]; int bi = 0;
        #pragma unroll
        for (int cls=1; cls<CC; ++cls) {
            float v = lg[cls] + sby[cls];
            if (v > bv) { bv = v; bi = cls; }
        }
        center[node] = bi;
    }
}

// ---------------- out accum: sum_r h[r] * Wc[r,:] ----------------
__global__ __launch_bounds__(256) void k_final(const float* __restrict__ H,
    const float* __restrict__ Wc, double* __restrict__ oacc)
{
    const int t = threadIdx.x;
    const v4f* Wc4 = (const v4f*)Wc;
    float a[8];
    #pragma unroll
    for (int c=0;c<8;++c) a[c]=0.f;
    const int E = NN*DD/4;               // quads of r
    for (int e = blockIdx.x*256 + t; e < E; e += gridDim.x*256) {
        int r = e*4;
        int node = r >> 7, d = r & 127;
        v4f h4 = __builtin_nontemporal_load(
            (const v4f*)&H[(((size_t)(d>>4)*NN + node) << 4) + (d & 15)]);
        float hh[4] = {h4.x, h4.y, h4.z, h4.w};
        #pragma unroll
        for (int j=0;j<4;++j) {
            float h = hh[j];
            v4f wa = __builtin_nontemporal_load(&Wc4[(size_t)(r+j)*2]);
            v4f wb = __builtin_nontemporal_load(&Wc4[(size_t)(r+j)*2 + 1]);
            a[0]+=h*wa.x; a[1]+=h*wa.y; a[2]+=h*wa.z; a[3]+=h*wa.w;
            a[4]+=h*wb.x; a[5]+=h*wb.y; a[6]+=h*wb.z; a[7]+=h*wb.w;
        }
    }
    #pragma unroll
    for (int off = 32; off > 0; off >>= 1)
        #pragma unroll
        for (int c=0;c<8;++c) a[c] += __shfl_down(a[c], off, 64);
    __shared__ double sred[4][8];
    const int wid = t >> 6, lane = t & 63;
    if (lane == 0) {
        #pragma unroll
        for (int c=0;c<8;++c) sred[wid][c] = (double)a[c];
    }
    __syncthreads();
    if (t < 8) {
        double s = sred[0][t]+sred[1][t]+sred[2][t]+sred[3][t];
        atomicAdd(&oacc[t], s);
    }
}

__global__ void k_fin(const double* __restrict__ oacc, const float* __restrict__ bc,
                      float* __restrict__ out)
{
    const int t = threadIdx.x;
    if (t < CC) out[t] = (float)(oacc[t] + (double)bc[t]);
}

extern "C" void kernel_launch(void* const* d_in, const int* in_sizes, int n_in,
                              void* d_out, int out_size, void* d_ws, size_t ws_size,
                              hipStream_t stream)
{
    const float* feat = (const float*)d_in[0];
    const float* Wg   = (const float*)d_in[1];
    const float* bg   = (const float*)d_in[2];
    const float* Wy   = (const float*)d_in[3];
    const float* by   = (const float*)d_in[4];
    const float* tau1 = (const float*)d_in[5];
    const float* tau2 = (const float*)d_in[6];
    const float* Wc   = (const float*)d_in[7];
    const float* bc   = (const float*)d_in[8];
    const int*   nb   = (const int*)d_in[9];

    char* ws = (char*)d_ws;
    float*    A      = (float*)(ws + A_OFF);
    float*    B      = (float*)(ws + B_OFF);
    int*      center = (int*)(ws + CENT_OFF);
    float*    z0     = (float*)(ws + Z0_OFF);
    float*    z1     = (float*)(ws + Z1_OFF);
    float*    f1     = (float*)(ws + F1_OFF);
    float*    f2     = (float*)(ws + F2_OFF);
    unsigned* su     = (unsigned*)(ws + SU_OFF);
    double*   sd     = (double*)(ws + SD_OFF);
    double*   oacc   = (double*)(ws + OACC_OFF);

    k_gemm<<<NB64, 256, 0, stream>>>(feat, Wg, A, oacc, su, sd);
    k_agg0<<<NB64, 256, 0, stream>>>(A, nb, bg, (const float4*)Wy, by, B, z0, center);

    float* hcur = B; float* hnext = A;
    float* zcur = z0; float* znext = z1;
    for (int it = 0; it < 3; ++it) {
        k_stats<<<(NN + 255)/256, 256, 0, stream>>>(center, nb, f1, f2, su + 2*it, sd + 2*it);
        k_update<<<NB64, 256, 0, stream>>>(hcur, hnext, nb, f1, f2, zcur, znext,
                                           su + 2*it, sd + 2*it, tau1, tau2,
                                           (const float4*)Wy, by, center);
        float* tmp = hcur; hcur = hnext; hnext = tmp;
        tmp = zcur; zcur = znext; znext = tmp;
    }
    k_final<<<2048, 256, 0, stream>>>(hcur, Wc, oacc);
    k_fin<<<1, 64, 0, stream>>>(oacc, bc, (float*)d_out);
}